// Round 8
// baseline (417.523 us; speedup 1.0000x reference)
//
#include <hip/hip_runtime.h>
#include <math.h>

typedef _Float16 f16;
typedef _Float16 f16x8 __attribute__((ext_vector_type(8)));
typedef float f32x4 __attribute__((ext_vector_type(4)));

#define KCODES 8192
#define DDIM   256
#define NTOT   16384
#define QT     64      // queries per block
#define NKT    32      // k-tiles of 256 codes
#define NCH    256     // total 32KB chunks = NKT*8
#define CHB    32768   // chunk image bytes: 2 planes * 256 codes * 32 d * 2B

#define F16_MIN_NORMAL 6.103515625e-05f

// ws layout: [0] loss | +256B e2[8192] f32 | z2[16384] f32 | +131072B emb-plane image (8 MB)

// z2[n]: exact (fp64) sum of fp32 squares, rounded once (rounds 2-7 verified). Also zeroes loss.
__global__ void z2_kernel(const float* __restrict__ z, float* __restrict__ z2out,
                          float* __restrict__ loss) {
    int n  = blockIdx.x * 256 + threadIdx.x;
    if (n == 0) loss[0] = 0.0f;
    int b  = n >> 10;
    int hw = n & 1023;
    const float* base = z + (size_t)b * DDIM * 1024 + hw;
    double acc = 0.0;
    #pragma unroll 8
    for (int d = 0; d < 256; ++d) {
        float v  = base[(size_t)d * 1024];
        float sq = __fmul_rn(v, v);
        acc += (double)sq;
    }
    z2out[n] = (float)acc;
}

// split emb into 2 fp16 planes (pre-scaled by 2^13) as the swizzled image; fused e2.
// Image layout bit-identical to rounds 3-7.
__global__ void esplit_kernel(const float* __restrict__ emb, char* __restrict__ img,
                              float* __restrict__ e2out) {
    __shared__ double part[4];
    int c = blockIdx.x, d = threadIdx.x;
    float ev = emb[(size_t)c * 256 + d];
    double sq = (double)__fmul_rn(ev, ev);
    #pragma unroll
    for (int off = 32; off > 0; off >>= 1) sq += __shfl_down(sq, off, 64);
    if ((d & 63) == 0) part[d >> 6] = sq;
    __syncthreads();
    if (d == 0) e2out[c] = (float)(part[0] + part[1] + part[2] + part[3]);
    float e = ev * 8192.0f;                               // exact pow2 scale
    float eh = 0.0f;
    if (fabsf(e) >= F16_MIN_NORMAL) eh = (float)(f16)e;   // normal-or-zero hi plane
    f16 ehh = (f16)eh;
    f16 emm = (f16)((e - eh) * 2048.0f);                  // residual scaled 2^11
    int kt = c >> 8, ch = d >> 5, ci = c & 255, dp = d & 31;
    char* p = img + (size_t)(kt * 8 + ch) * CHB;
    int off2 = (ci * 64 + dp * 2) ^ ((ci & 7) << 4);      // XOR swizzle (bits 4-6)
    *(f16*)(p + off2) = ehh;
    *(f16*)(p + 16384 + off2) = emm;
}

// Round-6 structure (8 waves, B reg-pipeline, per-k-tile pacing barrier) + A reg-pipeline:
// phase t issues B(t+1) global loads and A(ch+1) ds_reads, MFMAs run on registers loaded
// in phase t-1 -> LDS/L2 latency hides under the MFMA cluster. Numerics bit-identical.
__launch_bounds__(512, 2)
__global__ void vq_main(const float* __restrict__ z, const float* __restrict__ emb,
                        const float* __restrict__ e2w, const float* __restrict__ z2w,
                        const char* __restrict__ img, float* __restrict__ loss_accum,
                        float* __restrict__ out0, float* __restrict__ out1) {
    __shared__ __align__(16) char zsH[32768];     // z hi plane  [64 q][256 d] f16, swizzled
    __shared__ __align__(16) char zsM[32768];     // z mid plane (scaled 2^11)
    __shared__ float redv[8][QT];
    __shared__ int   redi[8][QT];
    __shared__ int   bidx[QT];
    __shared__ float wsum[8];

    const int tid  = threadIdx.x;
    const int w    = tid >> 6;
    const int lane = tid & 63;
    const int l15  = lane & 15;
    const int lg   = lane >> 4;
    const int nb   = blockIdx.x * QT;
    const int b    = nb >> 10;
    const int hw0  = nb & 1023;

    // per-lane B read offsets (fixed per chunk; same formula as rounds 3-7)
    int boff[2];
    #pragma unroll
    for (int n = 0; n < 2; ++n) {
        const int c = w * 32 + n * 16 + l15;
        boff[n] = (c * 64 + lg * 16) ^ ((c & 7) << 4);
    }

    // ---- build z fp16 planes in LDS (bit-identical to rounds 3-7) ----
    {
        const int q = tid & 63, dg = tid >> 6;
        #pragma unroll
        for (int i = 0; i < 32; ++i) {
            const int d = dg + i * 8;
            float zv = z[(size_t)(b * 256 + d) * 1024 + hw0 + q];
            float zh = 0.0f;
            if (fabsf(zv) >= F16_MIN_NORMAL) zh = (float)(f16)zv;
            const int off = (q * 512 + d * 2) ^ ((q & 7) << 4);
            *(f16*)(zsH + off) = (f16)zh;
            *(f16*)(zsM + off) = (f16)((zv - zh) * 2048.0f);
        }
    }

    float z2r[4][4];
    #pragma unroll
    for (int m = 0; m < 4; ++m)
        #pragma unroll
        for (int r = 0; r < 4; ++r)
            z2r[m][r] = z2w[nb + m * 16 + lg * 4 + r];

    float bestv[4][4];
    int   besti[4][4];
    #pragma unroll
    for (int m = 0; m < 4; ++m)
        #pragma unroll
        for (int r = 0; r < 4; ++r) { bestv[m][r] = INFINITY; besti[m][r] = 0; }

    // B register double-buffer: prefetch chunk 0 (issued before the barrier for latency)
    f16x8 bhA[2], bmA[2], bhB[2], bmB[2];
    #pragma unroll
    for (int n = 0; n < 2; ++n) {
        bhA[n] = *(const f16x8*)(img + boff[n]);
        bmA[n] = *(const f16x8*)(img + 16384 + boff[n]);
    }

    __syncthreads();   // z planes published

    // A register double-buffer: prefetch ch 0 fragments
    f16x8 ahA[4], amA[4], ahB[4], amB[4];
    #pragma unroll
    for (int m = 0; m < 4; ++m) {
        const int q = m * 16 + l15;
        const int off = (q * 512 + (lg * 8) * 2) ^ ((q & 7) << 4);
        ahA[m] = *(const f16x8*)(zsH + off);
        amA[m] = *(const f16x8*)(zsM + off);
    }

// phase t: issue B(t+1)->NXT B regs, issue A(ch+1)->NXT A regs, MFMA on CUR regs
// (loaded in phase t-1; >=1 full phase of latency slack). A-frags depend only on
// ch (z static) so the pipeline wraps cleanly at k-tile boundaries.
#define PHASE(CH, CAH, CAM, NAH, NAM, CBH, CBM, NBH, NBM)                                  \
    {                                                                                      \
        const int t  = kt * 8 + (CH);                                                      \
        const int tn = (t + 1 < NCH) ? (t + 1) : 0;                                        \
        const char* nbase = img + (size_t)tn * CHB;                                        \
        _Pragma("unroll")                                                                  \
        for (int n = 0; n < 2; ++n) {                                                      \
            NBH[n] = *(const f16x8*)(nbase + boff[n]);                                     \
            NBM[n] = *(const f16x8*)(nbase + 16384 + boff[n]);                             \
        }                                                                                  \
        const int chn = ((CH) + 1) & 7;                                                    \
        _Pragma("unroll")                                                                  \
        for (int m = 0; m < 4; ++m) {                                                      \
            const int q = m * 16 + l15;                                                    \
            const int off = (q * 512 + (chn * 32 + lg * 8) * 2) ^ ((q & 7) << 4);          \
            NAH[m] = *(const f16x8*)(zsH + off);                                           \
            NAM[m] = *(const f16x8*)(zsM + off);                                           \
        }                                                                                  \
        __builtin_amdgcn_s_setprio(1);                                                     \
        _Pragma("unroll")                                                                  \
        for (int m = 0; m < 4; ++m)                                                        \
            _Pragma("unroll")                                                              \
            for (int n = 0; n < 2; ++n) {                                                  \
                a1[m][n] = __builtin_amdgcn_mfma_f32_16x16x32_f16(CAH[m], CBH[n], a1[m][n], 0, 0, 0); \
                a2[m][n] = __builtin_amdgcn_mfma_f32_16x16x32_f16(CAH[m], CBM[n], a2[m][n], 0, 0, 0); \
                a2[m][n] = __builtin_amdgcn_mfma_f32_16x16x32_f16(CAM[m], CBH[n], a2[m][n], 0, 0, 0); \
                a3[m][n] = __builtin_amdgcn_mfma_f32_16x16x32_f16(CAM[m], CBM[n], a3[m][n], 0, 0, 0); \
            }                                                                              \
        __builtin_amdgcn_s_setprio(0);                                                     \
    }

    for (int kt = 0; kt < NKT; ++kt) {
        f32x4 a1[4][2], a2[4][2], a3[4][2];
        const f32x4 vz = {0.0f, 0.0f, 0.0f, 0.0f};
        #pragma unroll
        for (int m = 0; m < 4; ++m)
            #pragma unroll
            for (int n = 0; n < 2; ++n) { a1[m][n] = vz; a2[m][n] = vz; a3[m][n] = vz; }

        float e2v[2];
        #pragma unroll
        for (int n = 0; n < 2; ++n)
            e2v[n] = e2w[kt * 256 + w * 32 + n * 16 + l15];

        PHASE(0, ahA, amA, ahB, amB, bhA, bmA, bhB, bmB)
        PHASE(1, ahB, amB, ahA, amA, bhB, bmB, bhA, bmA)
        PHASE(2, ahA, amA, ahB, amB, bhA, bmA, bhB, bmB)
        PHASE(3, ahB, amB, ahA, amA, bhB, bmB, bhA, bmA)
        PHASE(4, ahA, amA, ahB, amB, bhA, bmA, bhB, bmB)
        PHASE(5, ahB, amB, ahA, amA, bhB, bmB, bhA, bmA)
        PHASE(6, ahA, amA, ahB, amB, bhA, bmA, bhB, bmB)
        PHASE(7, ahB, amB, ahA, amA, bhB, bmB, bhA, bmA)

        // ---- per-k-tile score + argmin (bit-identical rounding to rounds 2-7) ----
        #pragma unroll
        for (int m = 0; m < 4; ++m)
            #pragma unroll
            for (int n = 0; n < 2; ++n) {
                const int code = kt * 256 + w * 32 + n * 16 + l15;
                #pragma unroll
                for (int r = 0; r < 4; ++r) {
                    float rr = fmaf(a3[m][n][r], 0x1p-11f, a2[m][n][r]);
                    rr = fmaf(rr, 0x1p-11f, a1[m][n][r]);           // dot * 2^13
                    float tt = fmaf(rr, -0x1p-12f, z2r[m][r]);      // = fl(z2 - 2*dot), single round
                    float s  = __fadd_rn(tt, e2v[n]);
                    if (s < bestv[m][r]) { bestv[m][r] = s; besti[m][r] = code; }
                }
            }

        // PACING barrier: re-align the 8 waves once per k-tile (bounds wave/block drift
        // so all blocks on an XCD stream the same image chunk through L2; round-6 verified
        // at 81 MB fetch). A/B prefetches legally stay in flight across it (regs + static LDS).
        __builtin_amdgcn_s_barrier();
    }
#undef PHASE

    // ---- cross-lane argmin within each 16-lane column group ----
    #pragma unroll
    for (int m = 0; m < 4; ++m)
        #pragma unroll
        for (int r = 0; r < 4; ++r) {
            float v = bestv[m][r]; int idx = besti[m][r];
            #pragma unroll
            for (int dlt = 1; dlt < 16; dlt <<= 1) {
                float v2 = __shfl_xor(v, dlt, 64);
                int   i2 = __shfl_xor(idx, dlt, 64);
                if (v2 < v || (v2 == v && i2 < idx)) { v = v2; idx = i2; }
            }
            if (l15 == 0) {
                const int q = m * 16 + lg * 4 + r;
                redv[w][q] = v; redi[w][q] = idx;
            }
        }
    __syncthreads();
    if (tid < QT) {
        float bv = redv[0][tid]; int bi = redi[0][tid];
        #pragma unroll
        for (int ww = 1; ww < 8; ++ww) {
            float v = redv[ww][tid]; int ii = redi[ww][tid];
            if (v < bv || (v == bv && ii < bi)) { bv = v; bi = ii; }
        }
        bidx[tid] = bi;
        out1[nb + tid] = (float)bi;
    }
    __syncthreads();

    // ---- fused epilogue: quantized_st + commit-loss partial (rounds 2-7 verified) ----
    {
        const int q = tid & 63, dg = tid >> 6;
        const int myidx = bidx[q];
        const float* erow = emb + (size_t)myidx * 256;
        float lsum = 0.0f;
        #pragma unroll
        for (int i = 0; i < 32; ++i) {
            const int d = dg + 8 * i;
            const size_t gi = (size_t)(b * 256 + d) * 1024 + hw0 + q;
            float zv = z[gi];
            float qv = erow[d];
            out0[gi] = zv + (qv - zv);
            float e = zv - qv;
            lsum += e * e;
        }
        #pragma unroll
        for (int off = 32; off > 0; off >>= 1) lsum += __shfl_down(lsum, off, 64);
        if (lane == 0) wsum[w] = lsum;
        __syncthreads();
        if (tid == 0) {
            float s = 0.0f;
            #pragma unroll
            for (int i = 0; i < 8; ++i) s += wsum[i];
            atomicAdd(loss_accum, s);
        }
    }
}

__global__ void loss_final(const float* __restrict__ loss_accum, float* __restrict__ out2) {
    out2[0] = loss_accum[0] * (1.0f / 4194304.0f);
}

extern "C" void kernel_launch(void* const* d_in, const int* in_sizes, int n_in,
                              void* d_out, int out_size, void* d_ws, size_t ws_size,
                              hipStream_t stream) {
    (void)in_sizes; (void)n_in; (void)out_size; (void)ws_size;
    const float* z   = (const float*)d_in[0];   // (16,256,32,32)
    const float* emb = (const float*)d_in[1];   // (8192,256)
    float* ws_f = (float*)d_ws;
    char*  wsb  = (char*)d_ws;
    float* loss = ws_f;                          // [0]
    float* e2   = ws_f + 64;                     // 8192 f32
    float* z2   = ws_f + 64 + KCODES;            // 16384 f32
    char*  img  = wsb + 131072;                  // 8 MB fp16-plane image
    float* out0 = (float*)d_out;                 // quantized_st: 4,194,304
    float* out1 = out0 + (size_t)4194304;        // indices:      16,384
    float* out2 = out1 + (size_t)16384;          // commit_loss:  1

    esplit_kernel<<<KCODES, 256, 0, stream>>>(emb, img, e2);
    z2_kernel<<<NTOT / 256, 256, 0, stream>>>(z, z2, loss);
    vq_main<<<NTOT / QT, 512, 0, stream>>>(z, emb, e2, z2, img, loss, out0, out1);
    loss_final<<<1, 1, 0, stream>>>(loss, out2);
}

// Round 9
// 278.162 us; speedup vs baseline: 1.5010x; 1.5010x over previous
//
#include <hip/hip_runtime.h>
#include <math.h>

typedef _Float16 f16;
typedef _Float16 f16x8 __attribute__((ext_vector_type(8)));
typedef float f32x4 __attribute__((ext_vector_type(4)));

#define KCODES 8192
#define DDIM   256
#define NTOT   16384
#define QT     64      // queries per block
#define NKT    32      // k-tiles of 256 codes
#define NCH    256     // total 32KB chunks = NKT*8
#define CHB    32768   // chunk image bytes: 2 planes * 256 codes * 32 d * 2B

#define F16_MIN_NORMAL 6.103515625e-05f

// ws layout: [0] loss | +256B e2[8192] f32 | z2[16384] f32 | +131072B emb-plane image (8 MB)

// z2[n]: exact (fp64) sum of fp32 squares, rounded once (rounds 2-8 verified). Also zeroes loss.
__global__ void z2_kernel(const float* __restrict__ z, float* __restrict__ z2out,
                          float* __restrict__ loss) {
    int n  = blockIdx.x * 256 + threadIdx.x;
    if (n == 0) loss[0] = 0.0f;
    int b  = n >> 10;
    int hw = n & 1023;
    const float* base = z + (size_t)b * DDIM * 1024 + hw;
    double acc = 0.0;
    #pragma unroll 8
    for (int d = 0; d < 256; ++d) {
        float v  = base[(size_t)d * 1024];
        float sq = __fmul_rn(v, v);
        acc += (double)sq;
    }
    z2out[n] = (float)acc;
}

// split emb into 2 fp16 planes (pre-scaled by 2^13) as the swizzled image; fused e2.
// Image layout bit-identical to rounds 3-8.
__global__ void esplit_kernel(const float* __restrict__ emb, char* __restrict__ img,
                              float* __restrict__ e2out) {
    __shared__ double part[4];
    int c = blockIdx.x, d = threadIdx.x;
    float ev = emb[(size_t)c * 256 + d];
    double sq = (double)__fmul_rn(ev, ev);
    #pragma unroll
    for (int off = 32; off > 0; off >>= 1) sq += __shfl_down(sq, off, 64);
    if ((d & 63) == 0) part[d >> 6] = sq;
    __syncthreads();
    if (d == 0) e2out[c] = (float)(part[0] + part[1] + part[2] + part[3]);
    float e = ev * 8192.0f;                               // exact pow2 scale
    float eh = 0.0f;
    if (fabsf(e) >= F16_MIN_NORMAL) eh = (float)(f16)e;   // normal-or-zero hi plane
    f16 ehh = (f16)eh;
    f16 emm = (f16)((e - eh) * 2048.0f);                  // residual scaled 2^11
    int kt = c >> 8, ch = d >> 5, ci = c & 255, dp = d & 31;
    char* p = img + (size_t)(kt * 8 + ch) * CHB;
    int off2 = (ci * 64 + dp * 2) ^ ((ci & 7) << 4);      // XOR swizzle (bits 4-6)
    *(f16*)(p + off2) = ehh;
    *(f16*)(p + 16384 + off2) = emm;
}

// Round-6 structure (8 waves, B reg double-buffer from L2-resident image, A from static
// z-LDS) with: vectorized z-build (b128 LDS writes), pacing barrier every 2 k-tiles
// (waves self-skew -> LDS drain overlaps other wave's MFMA; block drift still bounded).
__launch_bounds__(512, 2)
__global__ void vq_main(const float* __restrict__ z, const float* __restrict__ emb,
                        const float* __restrict__ e2w, const float* __restrict__ z2w,
                        const char* __restrict__ img, float* __restrict__ loss_accum,
                        float* __restrict__ out0, float* __restrict__ out1) {
    __shared__ __align__(16) char zsH[32768];     // z hi plane  [64 q][256 d] f16, swizzled
    __shared__ __align__(16) char zsM[32768];     // z mid plane (scaled 2^11)
    __shared__ float redv[8][QT];
    __shared__ int   redi[8][QT];
    __shared__ int   bidx[QT];
    __shared__ float wsum[8];

    const int tid  = threadIdx.x;
    const int w    = tid >> 6;
    const int lane = tid & 63;
    const int l15  = lane & 15;
    const int lg   = lane >> 4;
    const int nb   = blockIdx.x * QT;
    const int b    = nb >> 10;
    const int hw0  = nb & 1023;

    // per-lane B read offsets (fixed per chunk; same formula as rounds 3-8)
    int boff[2];
    #pragma unroll
    for (int n = 0; n < 2; ++n) {
        const int c = w * 32 + n * 16 + l15;
        boff[n] = (c * 64 + lg * 16) ^ ((c & 7) << 4);
    }

    // ---- build z fp16 planes in LDS: vectorized b128 writes ----
    // Same (q,d) values and offsets as rounds 3-8 (bit-identical LDS image);
    // 8 ds_write_b128 per thread instead of 64 ds_write_b16.
    {
        const int q = tid & 63, dg = tid >> 6;    // dg 0..7
        #pragma unroll
        for (int g = 0; g < 4; ++g) {
            const int d0 = (dg + g * 8) * 8;      // 8 consecutive d
            f16 hv[8], mv[8];
            #pragma unroll
            for (int j = 0; j < 8; ++j) {
                float zv = z[(size_t)(b * 256 + d0 + j) * 1024 + hw0 + q];
                float zh = 0.0f;
                if (fabsf(zv) >= F16_MIN_NORMAL) zh = (float)(f16)zv;
                hv[j] = (f16)zh;
                mv[j] = (f16)((zv - zh) * 2048.0f);
            }
            const int off = (q * 512 + d0 * 2) ^ ((q & 7) << 4);  // 16B-aligned, swizzle-constant
            *(f16x8*)(zsH + off) = *(const f16x8*)hv;
            *(f16x8*)(zsM + off) = *(const f16x8*)mv;
        }
    }

    float z2r[4][4];
    #pragma unroll
    for (int m = 0; m < 4; ++m)
        #pragma unroll
        for (int r = 0; r < 4; ++r)
            z2r[m][r] = z2w[nb + m * 16 + lg * 4 + r];

    float bestv[4][4];
    int   besti[4][4];
    #pragma unroll
    for (int m = 0; m < 4; ++m)
        #pragma unroll
        for (int r = 0; r < 4; ++r) { bestv[m][r] = INFINITY; besti[m][r] = 0; }

    // B register double-buffer: prefetch chunk 0
    f16x8 bhA[2], bmA[2], bhB[2], bmB[2];
    #pragma unroll
    for (int n = 0; n < 2; ++n) {
        bhA[n] = *(const f16x8*)(img + boff[n]);
        bmA[n] = *(const f16x8*)(img + 16384 + boff[n]);
    }

    __syncthreads();   // z planes published

// one pipeline phase: prefetch B(t+1) into NXT regs, read A(t) from static z-LDS, MFMA with CUR
#define PHASE(CH, CURH, CURM, NXTH, NXTM)                                                  \
    {                                                                                      \
        const int t  = kt * 8 + (CH);                                                      \
        const int tn = (t + 1 < NCH) ? (t + 1) : 0;                                        \
        const char* nbase = img + (size_t)tn * CHB;                                        \
        _Pragma("unroll")                                                                  \
        for (int n = 0; n < 2; ++n) {                                                      \
            NXTH[n] = *(const f16x8*)(nbase + boff[n]);                                    \
            NXTM[n] = *(const f16x8*)(nbase + 16384 + boff[n]);                            \
        }                                                                                  \
        f16x8 ah[4], am[4];                                                                \
        _Pragma("unroll")                                                                  \
        for (int m = 0; m < 4; ++m) {                                                      \
            const int q = m * 16 + l15;                                                    \
            const int off = (q * 512 + ((CH) * 32 + lg * 8) * 2) ^ ((q & 7) << 4);         \
            ah[m] = *(const f16x8*)(zsH + off);                                            \
            am[m] = *(const f16x8*)(zsM + off);                                            \
        }                                                                                  \
        __builtin_amdgcn_s_setprio(1);                                                     \
        _Pragma("unroll")                                                                  \
        for (int m = 0; m < 4; ++m)                                                        \
            _Pragma("unroll")                                                              \
            for (int n = 0; n < 2; ++n) {                                                  \
                a1[m][n] = __builtin_amdgcn_mfma_f32_16x16x32_f16(ah[m], CURH[n], a1[m][n], 0, 0, 0); \
                a2[m][n] = __builtin_amdgcn_mfma_f32_16x16x32_f16(ah[m], CURM[n], a2[m][n], 0, 0, 0); \
                a2[m][n] = __builtin_amdgcn_mfma_f32_16x16x32_f16(am[m], CURH[n], a2[m][n], 0, 0, 0); \
                a3[m][n] = __builtin_amdgcn_mfma_f32_16x16x32_f16(am[m], CURM[n], a3[m][n], 0, 0, 0); \
            }                                                                              \
        __builtin_amdgcn_s_setprio(0);                                                     \
    }

    for (int kt = 0; kt < NKT; ++kt) {
        f32x4 a1[4][2], a2[4][2], a3[4][2];
        const f32x4 vz = {0.0f, 0.0f, 0.0f, 0.0f};
        #pragma unroll
        for (int m = 0; m < 4; ++m)
            #pragma unroll
            for (int n = 0; n < 2; ++n) { a1[m][n] = vz; a2[m][n] = vz; a3[m][n] = vz; }

        float e2v[2];
        #pragma unroll
        for (int n = 0; n < 2; ++n)
            e2v[n] = e2w[kt * 256 + w * 32 + n * 16 + l15];

        PHASE(0, bhA, bmA, bhB, bmB)
        PHASE(1, bhB, bmB, bhA, bmA)
        PHASE(2, bhA, bmA, bhB, bmB)
        PHASE(3, bhB, bmB, bhA, bmA)
        PHASE(4, bhA, bmA, bhB, bmB)
        PHASE(5, bhB, bmB, bhA, bmA)
        PHASE(6, bhA, bmA, bhB, bmB)
        PHASE(7, bhB, bmB, bhA, bmA)

        // ---- per-k-tile score + argmin (bit-identical rounding to rounds 2-8) ----
        #pragma unroll
        for (int m = 0; m < 4; ++m)
            #pragma unroll
            for (int n = 0; n < 2; ++n) {
                const int code = kt * 256 + w * 32 + n * 16 + l15;
                #pragma unroll
                for (int r = 0; r < 4; ++r) {
                    float rr = fmaf(a3[m][n][r], 0x1p-11f, a2[m][n][r]);
                    rr = fmaf(rr, 0x1p-11f, a1[m][n][r]);           // dot * 2^13
                    float tt = fmaf(rr, -0x1p-12f, z2r[m][r]);      // = fl(z2 - 2*dot), single round
                    float s  = __fadd_rn(tt, e2v[n]);
                    if (s < bestv[m][r]) { bestv[m][r] = s; besti[m][r] = code; }
                }
            }

        // PACING barrier every 2 k-tiles: bounds wave/block drift (L2 chunk locality,
        // round-6 verified) while letting waves self-skew within the window so one
        // wave's MFMA covers the other's LDS/L2 latency.
        if (kt & 1) __builtin_amdgcn_s_barrier();
    }
#undef PHASE

    // ---- cross-lane argmin within each 16-lane column group ----
    #pragma unroll
    for (int m = 0; m < 4; ++m)
        #pragma unroll
        for (int r = 0; r < 4; ++r) {
            float v = bestv[m][r]; int idx = besti[m][r];
            #pragma unroll
            for (int dlt = 1; dlt < 16; dlt <<= 1) {
                float v2 = __shfl_xor(v, dlt, 64);
                int   i2 = __shfl_xor(idx, dlt, 64);
                if (v2 < v || (v2 == v && i2 < idx)) { v = v2; idx = i2; }
            }
            if (l15 == 0) {
                const int q = m * 16 + lg * 4 + r;
                redv[w][q] = v; redi[w][q] = idx;
            }
        }
    __syncthreads();
    if (tid < QT) {
        float bv = redv[0][tid]; int bi = redi[0][tid];
        #pragma unroll
        for (int ww = 1; ww < 8; ++ww) {
            float v = redv[ww][tid]; int ii = redi[ww][tid];
            if (v < bv || (v == bv && ii < bi)) { bv = v; bi = ii; }
        }
        bidx[tid] = bi;
        out1[nb + tid] = (float)bi;
    }
    __syncthreads();

    // ---- fused epilogue: quantized_st + commit-loss partial (float4 erow reads) ----
    {
        const int q = tid & 63, dg = tid >> 6;    // dg 0..7 -> 32 consecutive d
        const int myidx = bidx[q];
        const float* erow = emb + (size_t)myidx * 256;
        float lsum = 0.0f;
        #pragma unroll
        for (int g = 0; g < 8; ++g) {
            const int d0 = dg * 32 + g * 4;
            float4 qv4 = *(const float4*)(erow + d0);
            #pragma unroll
            for (int j = 0; j < 4; ++j) {
                const int d = d0 + j;
                const size_t gi = (size_t)(b * 256 + d) * 1024 + hw0 + q;
                float zv = z[gi];
                float qv = (&qv4.x)[j];
                out0[gi] = zv + (qv - zv);
                float e = zv - qv;
                lsum += e * e;
            }
        }
        #pragma unroll
        for (int off = 32; off > 0; off >>= 1) lsum += __shfl_down(lsum, off, 64);
        if (lane == 0) wsum[w] = lsum;
        __syncthreads();
        if (tid == 0) {
            float s = 0.0f;
            #pragma unroll
            for (int i = 0; i < 8; ++i) s += wsum[i];
            atomicAdd(loss_accum, s);
        }
    }
}

__global__ void loss_final(const float* __restrict__ loss_accum, float* __restrict__ out2) {
    out2[0] = loss_accum[0] * (1.0f / 4194304.0f);
}

extern "C" void kernel_launch(void* const* d_in, const int* in_sizes, int n_in,
                              void* d_out, int out_size, void* d_ws, size_t ws_size,
                              hipStream_t stream) {
    (void)in_sizes; (void)n_in; (void)out_size; (void)ws_size;
    const float* z   = (const float*)d_in[0];   // (16,256,32,32)
    const float* emb = (const float*)d_in[1];   // (8192,256)
    float* ws_f = (float*)d_ws;
    char*  wsb  = (char*)d_ws;
    float* loss = ws_f;                          // [0]
    float* e2   = ws_f + 64;                     // 8192 f32
    float* z2   = ws_f + 64 + KCODES;            // 16384 f32
    char*  img  = wsb + 131072;                  // 8 MB fp16-plane image
    float* out0 = (float*)d_out;                 // quantized_st: 4,194,304
    float* out1 = out0 + (size_t)4194304;        // indices:      16,384
    float* out2 = out1 + (size_t)16384;          // commit_loss:  1

    esplit_kernel<<<KCODES, 256, 0, stream>>>(emb, img, e2);
    z2_kernel<<<NTOT / 256, 256, 0, stream>>>(z, z2, loss);
    vq_main<<<NTOT / QT, 512, 0, stream>>>(z, emb, e2, z2, img, loss, out0, out1);
    loss_final<<<1, 1, 0, stream>>>(loss, out2);
}